// Round 1
// baseline (768.074 us; speedup 1.0000x reference)
//
#include <hip/hip_runtime.h>

#define NN 100000
#define NE 3200000
#define DD 64

// ---------------------------------------------------------------------------
// Detect whether adj_row/adj_col were delivered as int64 (8B) or int32 (4B).
// If int64: element NE/4 occupies int32 slots [NE/2, NE/2+1]; its high word
// is 0 and its low word ~25000 != 0. If int32: both slots hold row values
// ~50000 != 0 (sorted mid-array). Reads stay within the first NE int32s,
// which is in-bounds for either layout.
// ---------------------------------------------------------------------------
__global__ void detect_kernel(const void* rowbuf, int* flag) {
    const int* p = (const int*)rowbuf;
    int lo = p[NE / 2];
    int hi = p[NE / 2 + 1];
    *flag = (hi == 0 && lo != 0) ? 1 : 0;
}

// ---------------------------------------------------------------------------
// row_ptr[r] = lower_bound(adj_row, r) for r in [0, NN]; row r owns edges
// [row_ptr[r], row_ptr[r+1]).  Deterministic, no atomics.
// ---------------------------------------------------------------------------
__global__ void rowptr_kernel(const void* rowbuf, const int* __restrict__ flag,
                              int* __restrict__ rp) {
    int r = blockIdx.x * blockDim.x + threadIdx.x;
    if (r > NN) return;
    int is64 = *flag;
    int lo = 0, hi = NE;
    if (is64) {
        const long long* row = (const long long*)rowbuf;
        while (lo < hi) {
            int mid = (lo + hi) >> 1;
            if (row[mid] < (long long)r) lo = mid + 1; else hi = mid;
        }
    } else {
        const int* row = (const int*)rowbuf;
        while (lo < hi) {
            int mid = (lo + hi) >> 1;
            if (row[mid] < r) lo = mid + 1; else hi = mid;
        }
    }
    rp[r] = lo;
}

// ---------------------------------------------------------------------------
// Y[row, :] = X[row, :] @ W   (D=64). One wave (64 lanes) per row; lane j
// computes output feature j. W staged in LDS (16 KB); x-row element k
// broadcast via __shfl. LDS read sW[k*64+lane] is 2-lanes/bank (free).
// ---------------------------------------------------------------------------
__global__ void gemm64_kernel(const float* __restrict__ X,
                              const float* __restrict__ W,
                              float* __restrict__ Y) {
    __shared__ float sW[DD * DD];
    for (int i = threadIdx.x; i < DD * DD; i += blockDim.x) sW[i] = W[i];
    __syncthreads();

    int wave = threadIdx.x >> 6;
    int lane = threadIdx.x & 63;
    int row  = blockIdx.x * (blockDim.x >> 6) + wave;
    if (row >= NN) return;

    float xv  = X[(size_t)row * DD + lane];
    float acc = 0.f;
#pragma unroll
    for (int k = 0; k < DD; ++k) {
        acc += __shfl(xv, k, 64) * sW[k * DD + lane];
    }
    Y[(size_t)row * DD + lane] = acc;
}

// ---------------------------------------------------------------------------
// out[row, :] = sum_{e in row} val[e] * S[col[e], :]  + bias  (+ LeakyReLU)
// One wave per row; lane = feature. Each edge is one coalesced 256 B gather
// of a support row (support fits in L3).
// ---------------------------------------------------------------------------
__global__ void spmm_kernel(const float* __restrict__ S, const void* colbuf,
                            const float* __restrict__ val,
                            const int* __restrict__ rp,
                            const int* __restrict__ flag,
                            const float* __restrict__ bias,
                            float* __restrict__ out, int leaky) {
    int wave = threadIdx.x >> 6;
    int lane = threadIdx.x & 63;
    int row  = blockIdx.x * (blockDim.x >> 6) + wave;
    if (row >= NN) return;

    int e0 = rp[row], e1 = rp[row + 1];
    int is64 = *flag;
    float acc = 0.f;
    if (is64) {
        const long long* col = (const long long*)colbuf;
        for (int e = e0; e < e1; ++e) {
            int c = (int)col[e];
            acc += val[e] * S[(size_t)c * DD + lane];
        }
    } else {
        const int* col = (const int*)colbuf;
        for (int e = e0; e < e1; ++e) {
            int c = col[e];
            acc += val[e] * S[(size_t)c * DD + lane];
        }
    }
    acc += bias[lane];
    if (leaky) acc = (acc >= 0.f) ? acc : 0.2f * acc;
    out[(size_t)row * DD + lane] = acc;
}

// ---------------------------------------------------------------------------
extern "C" void kernel_launch(void* const* d_in, const int* in_sizes, int n_in,
                              void* d_out, int out_size, void* d_ws, size_t ws_size,
                              hipStream_t stream) {
    const float* x       = (const float*)d_in[0];
    const void*  adj_row = d_in[1];
    const void*  adj_col = d_in[2];
    const float* adj_val = (const float*)d_in[3];
    const float* W1      = (const float*)d_in[4];
    const float* b1      = (const float*)d_in[5];
    const float* W2      = (const float*)d_in[6];
    const float* b2      = (const float*)d_in[7];
    float*       out     = (float*)d_out;

    // workspace layout: support buffer [NN*DD f32] | row_ptr [NN+1 int] | flag
    float* sup  = (float*)d_ws;
    int*   rp   = (int*)((char*)d_ws + (size_t)NN * DD * sizeof(float));
    int*   flag = rp + (NN + 1);

    detect_kernel<<<1, 1, 0, stream>>>(adj_row, flag);

    rowptr_kernel<<<(NN + 1 + 255) / 256, 256, 0, stream>>>(adj_row, flag, rp);

    const int ROWS_PER_BLOCK = 4;                       // 256 threads = 4 waves
    const int grid = (NN + ROWS_PER_BLOCK - 1) / ROWS_PER_BLOCK;

    // layer 1: sup = x @ W1 ; h(=d_out) = spmm(sup) + b1, LeakyReLU
    gemm64_kernel<<<grid, 256, 0, stream>>>(x, W1, sup);
    spmm_kernel<<<grid, 256, 0, stream>>>(sup, adj_col, adj_val, rp, flag, b1, out, 1);

    // layer 2: sup = h @ W2 ; out = spmm(sup) + b2
    gemm64_kernel<<<grid, 256, 0, stream>>>(out, W2, sup);
    spmm_kernel<<<grid, 256, 0, stream>>>(sup, adj_col, adj_val, rp, flag, b2, out, 0);
}

// Round 2
// 363.509 us; speedup vs baseline: 2.1129x; 2.1129x over previous
//
#include <hip/hip_runtime.h>

#define NN 100000
#define NE 3200000
#define DD 64

// ---------------------------------------------------------------------------
// Detect whether adj_row/adj_col were delivered as int64 (8B) or int32 (4B).
// If int64: int32 slots [NE/2, NE/2+1] hold {low word != 0, high word == 0}.
// If int32: both slots hold row values ~50000 != 0 (sorted, mid-array).
// ---------------------------------------------------------------------------
__global__ void detect_kernel(const void* rowbuf, int* flag) {
    const int* p = (const int*)rowbuf;
    int lo = p[NE / 2];
    int hi = p[NE / 2 + 1];
    *flag = (hi == 0 && lo != 0) ? 1 : 0;
}

// ---------------------------------------------------------------------------
// row_ptr[r] = lower_bound(adj_row, r); row r owns edges [rp[r], rp[r+1]).
// ---------------------------------------------------------------------------
__global__ void rowptr_kernel(const void* rowbuf, const int* __restrict__ flag,
                              int* __restrict__ rp) {
    int r = blockIdx.x * blockDim.x + threadIdx.x;
    if (r > NN) return;
    int is64 = *flag;
    int lo = 0, hi = NE;
    if (is64) {
        const long long* row = (const long long*)rowbuf;
        while (lo < hi) {
            int mid = (lo + hi) >> 1;
            if (row[mid] < (long long)r) lo = mid + 1; else hi = mid;
        }
    } else {
        const int* row = (const int*)rowbuf;
        while (lo < hi) {
            int mid = (lo + hi) >> 1;
            if (row[mid] < r) lo = mid + 1; else hi = mid;
        }
    }
    rp[r] = lo;
}

// ---------------------------------------------------------------------------
// Edge accumulation: 4 subgroups of 16 lanes; subgroup `sub` processes edges
// e0+sub, e0+sub+4, ...; each lane gathers float4 (16 lanes x 16B = one 256B
// row). Unrolled x2 -> up to 8 independent gathers in flight per wave.
// ---------------------------------------------------------------------------
template <typename CT>
__device__ inline void edge_accum(const float* __restrict__ X,
                                  const CT* __restrict__ col,
                                  const float* __restrict__ val,
                                  int e0, int e1, int sub, int sl,
                                  float4& acc) {
    int e = e0 + sub;
    for (; e + 4 < e1; e += 8) {
        int   c0 = (int)col[e];     float v0 = val[e];
        int   c1 = (int)col[e + 4]; float v1 = val[e + 4];
        float4 g0 = *(const float4*)(X + (size_t)c0 * DD + sl * 4);
        float4 g1 = *(const float4*)(X + (size_t)c1 * DD + sl * 4);
        acc.x = fmaf(v0, g0.x, acc.x); acc.y = fmaf(v0, g0.y, acc.y);
        acc.z = fmaf(v0, g0.z, acc.z); acc.w = fmaf(v0, g0.w, acc.w);
        acc.x = fmaf(v1, g1.x, acc.x); acc.y = fmaf(v1, g1.y, acc.y);
        acc.z = fmaf(v1, g1.z, acc.z); acc.w = fmaf(v1, g1.w, acc.w);
    }
    if (e < e1) {
        int c = (int)col[e]; float v = val[e];
        float4 g = *(const float4*)(X + (size_t)c * DD + sl * 4);
        acc.x = fmaf(v, g.x, acc.x); acc.y = fmaf(v, g.y, acc.y);
        acc.z = fmaf(v, g.z, acc.z); acc.w = fmaf(v, g.w, acc.w);
    }
}

// ---------------------------------------------------------------------------
// Fused GCN layer:  out[row,:] = act( (sum_e val[e]*X[col[e],:]) @ W + b )
// Uses A(xW) = (Ax)W.  One wave per row. After edge accumulation + shfl_xor
// reduction, lane (k>>2) component (k&3) holds h[k]; the W-multiply is a
// 64-step shfl-broadcast + LDS FMA (sW[k*64+lane]: stride-1, 2-way bank
// aliasing = free).
// ---------------------------------------------------------------------------
__global__ __launch_bounds__(256) void fused_layer_kernel(
    const float* __restrict__ X, const void* colbuf,
    const float* __restrict__ val, const int* __restrict__ rp,
    const int* __restrict__ flag, const float* __restrict__ W,
    const float* __restrict__ bias, float* __restrict__ out, int leaky) {
    __shared__ float sW[DD * DD];
    for (int i = threadIdx.x; i < DD * DD; i += blockDim.x) sW[i] = W[i];
    __syncthreads();

    int wave = threadIdx.x >> 6;
    int lane = threadIdx.x & 63;
    int row  = blockIdx.x * (blockDim.x >> 6) + wave;
    if (row >= NN) return;

    int sub = lane >> 4;   // 0..3  (edge slot)
    int sl  = lane & 15;   // 0..15 (feature quad)
    int e0 = rp[row], e1 = rp[row + 1];

    float4 acc = make_float4(0.f, 0.f, 0.f, 0.f);
    if (*flag) {
        edge_accum(X, (const long long*)colbuf, val, e0, e1, sub, sl, acc);
    } else {
        edge_accum(X, (const int*)colbuf, val, e0, e1, sub, sl, acc);
    }

    // reduce across the 4 subgroups (masks 16, 32) -> every lane has full sums
    acc.x += __shfl_xor(acc.x, 16); acc.y += __shfl_xor(acc.y, 16);
    acc.z += __shfl_xor(acc.z, 16); acc.w += __shfl_xor(acc.w, 16);
    acc.x += __shfl_xor(acc.x, 32); acc.y += __shfl_xor(acc.y, 32);
    acc.z += __shfl_xor(acc.z, 32); acc.w += __shfl_xor(acc.w, 32);

    // y[lane] = b[lane] + sum_k h[k] * W[k][lane]
    float y = bias[lane];
#pragma unroll
    for (int k4 = 0; k4 < 16; ++k4) {
        float h0 = __shfl(acc.x, k4, 64);
        float h1 = __shfl(acc.y, k4, 64);
        float h2 = __shfl(acc.z, k4, 64);
        float h3 = __shfl(acc.w, k4, 64);
        y = fmaf(h0, sW[(k4 * 4 + 0) * DD + lane], y);
        y = fmaf(h1, sW[(k4 * 4 + 1) * DD + lane], y);
        y = fmaf(h2, sW[(k4 * 4 + 2) * DD + lane], y);
        y = fmaf(h3, sW[(k4 * 4 + 3) * DD + lane], y);
    }

    if (leaky) y = (y >= 0.f) ? y : 0.2f * y;
    out[(size_t)row * DD + lane] = y;
}

// ---------------------------------------------------------------------------
extern "C" void kernel_launch(void* const* d_in, const int* in_sizes, int n_in,
                              void* d_out, int out_size, void* d_ws, size_t ws_size,
                              hipStream_t stream) {
    const float* x       = (const float*)d_in[0];
    const void*  adj_row = d_in[1];
    const void*  adj_col = d_in[2];
    const float* adj_val = (const float*)d_in[3];
    const float* W1      = (const float*)d_in[4];
    const float* b1      = (const float*)d_in[5];
    const float* W2      = (const float*)d_in[6];
    const float* b2      = (const float*)d_in[7];
    float*       out     = (float*)d_out;

    // workspace: h buffer [NN*DD f32] | row_ptr [NN+1 int] | flag [1 int]
    float* h    = (float*)d_ws;
    int*   rp   = (int*)((char*)d_ws + (size_t)NN * DD * sizeof(float));
    int*   flag = rp + (NN + 1);

    detect_kernel<<<1, 1, 0, stream>>>(adj_row, flag);
    rowptr_kernel<<<(NN + 1 + 255) / 256, 256, 0, stream>>>(adj_row, flag, rp);

    const int grid = (NN + 3) / 4;  // 4 waves (rows) per 256-thread block

    // layer 1: h = LeakyReLU( (A x) W1 + b1 )
    fused_layer_kernel<<<grid, 256, 0, stream>>>(x, adj_col, adj_val, rp, flag,
                                                 W1, b1, h, 1);
    // layer 2: out = (A h) W2 + b2
    fused_layer_kernel<<<grid, 256, 0, stream>>>(h, adj_col, adj_val, rp, flag,
                                                 W2, b2, out, 0);
}